// Round 9
// baseline (6423.880 us; speedup 1.0000x reference)
//
#include <hip/hip_runtime.h>
#include <hip/hip_bf16.h>
#include <math.h>

// ---------------- constants ----------------
#define PI_F 3.14159265358979323846f
#define TWO_PI_F 6.283185307179586f

constexpr int BB = 4;            // batch
constexpr int FF_ = 2048;        // frames
constexpr int RC = 512;          // rnn channels
constexpr int HOP = 256;
constexpr int KK = 1024;         // FIR len
constexpr int LL = HOP + KK - 1; // 1279
constexpr size_t TOT = 525311;   // (F-1)*HOP + L
constexpr int APAD = 24064;      // zero pad in front of audio rows (>= REV-1, mult of 64)
constexpr size_t AROW = 549376;  // APAD + 525312
constexpr int REV = 24000;

// output offsets (floats)
constexpr size_t O1 = 2101244;   // oq
constexpr size_t O2 = 2109436;   // v_gain
constexpr size_t O3 = 2117628;   // u_gain
constexpr size_t O4 = 2125820;   // ff
constexpr size_t O5 = 2158588;   // fb

// workspace offsets (bytes)
constexpr size_t OFF_X      = 0;                 // 8192*512*4
constexpr size_t OFF_GI     = 16777216;          // 8192*1536*4
constexpr size_t OFF_HS     = 67108864;          // 8192*512*4
constexpr size_t OFF_FILTR  = 0;                 // 8192*1024*4 (overlays X/GI, dead by then)
constexpr size_t OFF_OQ     = 83886080;
constexpr size_t OFF_VG     = 83918848;
constexpr size_t OFF_UG     = 83951616;
constexpr size_t OFF_FFW    = 83984384;          // also hbuf (16KB) during k_gru; ffw written after
constexpr size_t OFF_FBW    = 84115456;
constexpr size_t OFF_START  = 84246528;
constexpr size_t OFF_F0M    = 84279296;
constexpr size_t OFF_EXC    = 84296192;          // 8192*256*4
constexpr size_t OFF_IRP    = 50331648;          // padded reverb ir — in gi dead-zone, used after k_gru
constexpr size_t OFF_AUDIO  = 92684800;          // 4*549376*4

constexpr size_t OFF_HBUF   = OFF_FFW;           // 2 slots x 4 batch x 256 words x 8B = 16KB

__device__ __forceinline__ float softplusf(float x) {
  return x > 20.0f ? x : log1pf(expf(x));
}
__device__ __forceinline__ float sigmoidf_(float x) {
  return 1.0f / (1.0f + expf(-x));
}

typedef _Float16 half2v __attribute__((ext_vector_type(2)));

__device__ __forceinline__ float dot2f(unsigned wa, unsigned hb, float acc) {
#if __has_builtin(__builtin_amdgcn_fdot2)
  union { unsigned u; half2v h; } A, B;
  A.u = wa; B.u = hb;
  return __builtin_amdgcn_fdot2(A.h, B.h, acc, false);
#else
  union { unsigned u; _Float16 h[2]; } A, B;
  A.u = wa; B.u = hb;
  return fmaf((float)A.h[0], (float)B.h[0], fmaf((float)A.h[1], (float)B.h[1], acc));
#endif
}

// ---------------- f0 mean per batch ----------------
__global__ __launch_bounds__(256) void k_f0mean(const float* __restrict__ f0, float* __restrict__ f0m) {
  int b = blockIdx.x, tid = threadIdx.x;
  float s = 0.f;
  for (int t = tid; t < FF_; t += 256) s += f0[b*FF_ + t];
  #pragma unroll
  for (int m = 1; m < 64; m <<= 1) s += __shfl_xor(s, m);
  __shared__ float ws4[4];
  if ((tid & 63) == 0) ws4[tid >> 6] = s;
  __syncthreads();
  if (tid == 0) f0m[b] = (ws4[0] + ws4[1] + ws4[2] + ws4[3]) * (1.0f / 2048.0f);
}

// ---------------- input projection: x = relu(concat @ W_in^T + b_in) ----------------
__global__ __launch_bounds__(256) void k_inproj(
    const float* __restrict__ f0, const float* __restrict__ loud,
    const float* __restrict__ gender, const float* __restrict__ age,
    const float* __restrict__ z, const float* __restrict__ f0m,
    const float* __restrict__ Win, const float* __restrict__ bin,
    float* __restrict__ x)
{
  __shared__ float inp[16 * 28];
  int r0 = blockIdx.x * 16;   // bf base
  int tid = threadIdx.x;
  for (int i = tid; i < 16 * 28; i += 256) {
    int r = i / 28, c = i % 28;
    int bf = r0 + r, b = bf >> 11;
    float v;
    if (c == 0)       v = f0[bf] - f0m[b];
    else if (c == 1)  v = loud[bf];
    else if (c < 4)   v = gender[(size_t)bf*2 + (c - 2)];
    else if (c < 12)  v = age[(size_t)bf*8 + (c - 4)];
    else              v = z[(size_t)bf*16 + (c - 12)];
    inp[i] = v;
  }
  __syncthreads();
  for (int o = tid; o < 16 * 512; o += 256) {
    int r = o >> 9, j = o & 511;
    const float* w = Win + j * 28;
    const float* ip = inp + r * 28;
    float a = bin[j];
    #pragma unroll
    for (int c2 = 0; c2 < 28; ++c2) a = fmaf(w[c2], ip[c2], a);
    x[(size_t)(r0 + r) * 512 + j] = fmaxf(a, 0.0f);
  }
}

// ---------------- GEMM: gi = x @ W_ih^T + b_ih  (M=8192, N=1536, K=512) ----------------
__global__ __launch_bounds__(256) void k_gemm_gi(
    const float* __restrict__ A, const float* __restrict__ Bw,
    const float* __restrict__ bias, float* __restrict__ C)
{
  __shared__ float As[32 * 68];
  __shared__ float Bs[32 * 68];
  int tid = threadIdx.x;
  int n0 = blockIdx.x * 64, m0 = blockIdx.y * 64;
  int tx = tid & 15, ty = tid >> 4;
  float c[4][4] = {{0.f}};
  for (int k0 = 0; k0 < 512; k0 += 32) {
    __syncthreads();
    for (int i = tid; i < 2048; i += 256) {
      int mm = i >> 5, kk = i & 31;
      As[kk * 68 + mm] = A[(size_t)(m0 + mm) * 512 + k0 + kk];
      Bs[kk * 68 + mm] = Bw[(size_t)(n0 + mm) * 512 + k0 + kk];
    }
    __syncthreads();
    #pragma unroll
    for (int kk = 0; kk < 32; ++kk) {
      float4 a = *(const float4*)&As[kk * 68 + ty * 4];
      float4 b = *(const float4*)&Bs[kk * 68 + tx * 4];
      c[0][0] = fmaf(a.x, b.x, c[0][0]); c[0][1] = fmaf(a.x, b.y, c[0][1]);
      c[0][2] = fmaf(a.x, b.z, c[0][2]); c[0][3] = fmaf(a.x, b.w, c[0][3]);
      c[1][0] = fmaf(a.y, b.x, c[1][0]); c[1][1] = fmaf(a.y, b.y, c[1][1]);
      c[1][2] = fmaf(a.y, b.z, c[1][2]); c[1][3] = fmaf(a.y, b.w, c[1][3]);
      c[2][0] = fmaf(a.z, b.x, c[2][0]); c[2][1] = fmaf(a.z, b.y, c[2][1]);
      c[2][2] = fmaf(a.z, b.z, c[2][2]); c[2][3] = fmaf(a.z, b.w, c[2][3]);
      c[3][0] = fmaf(a.w, b.x, c[3][0]); c[3][1] = fmaf(a.w, b.y, c[3][1]);
      c[3][2] = fmaf(a.w, b.z, c[3][2]); c[3][3] = fmaf(a.w, b.w, c[3][3]);
    }
  }
  int n = n0 + tx * 4;
  float4 bb = *(const float4*)&bias[n];
  #pragma unroll
  for (int mi = 0; mi < 4; ++mi) {
    int m = m0 + ty * 4 + mi;
    float4 v;
    v.x = c[mi][0] + bb.x; v.y = c[mi][1] + bb.y;
    v.z = c[mi][2] + bb.z; v.w = c[mi][3] + bb.w;
    *(float4*)&C[(size_t)m * 1536 + n] = v;
  }
}

// ---------------- persistent GRU v8: unit-owner threads, 1 barrier/step ----------------
// 4 groups (batches) x 16 WGs (32 units each). Sync: tagged {f16x2,step}
// words, ONE relaxed agent-scope poll per thread (unchanged, proven).
// Dot layout: thread (u=tid>>3, piece=tid&7) owns ALL 3 gate rows of unit u
// for one 64-float k-piece -> each uint4 h load feeds 12 dot2s. The 8 pieces
// of a unit are 8 adjacent lanes -> gate sums reduce with 3 shfl_xor (no red
// LDS roundtrip, no 2nd barrier); the piece==0 lane runs the cell + publish
// immediately. Cross-iteration LDS reuse ordered by the single per-step
// barrier; hbuf lap safety by tag induction as before.
__global__ __launch_bounds__(256, 1) void k_gru(
    const float* __restrict__ Whh, const float* __restrict__ bhh,
    const float* __restrict__ gi, float* __restrict__ hs,
    unsigned long long* hbuf)
{
  __shared__ unsigned hs2[2][292];   // 8 pieces x 36-dword stride per parity

  const int tid = threadIdx.x;
  const int b   = blockIdx.x & 3;    // batch / group
  const int wgi = blockIdx.x >> 2;   // 0..15
  const int u0  = wgi * 32;
  const int piece = tid & 7;
  const int u     = tid >> 3;        // 0..31

  // per-thread weights: 3 gate rows of unit u, k-piece [64*piece, +64)
  unsigned wr0[32], wr1[32], wr2[32];
  {
    const float* s0 = Whh + (size_t)(u0 + u) * 512 + piece * 64;
    const float* s1 = Whh + (size_t)(512 + u0 + u) * 512 + piece * 64;
    const float* s2 = Whh + (size_t)(1024 + u0 + u) * 512 + piece * 64;
    #pragma unroll
    for (int j = 0; j < 32; ++j) {
      float2 a = *(const float2*)(s0 + 2 * j);
      float2 c = *(const float2*)(s1 + 2 * j);
      float2 d = *(const float2*)(s2 + 2 * j);
      union { unsigned u32; _Float16 hh[2]; } ca, cb, cc;
      ca.hh[0] = (_Float16)a.x; ca.hh[1] = (_Float16)a.y;
      cb.hh[0] = (_Float16)c.x; cb.hh[1] = (_Float16)c.y;
      cc.hh[0] = (_Float16)d.x; cc.hh[1] = (_Float16)d.y;
      wr0[j] = ca.u32; wr1[j] = cb.u32; wr2[j] = cc.u32;
    }
  }
  const float b_r = bhh[u0 + u];
  const float b_z = bhh[512 + u0 + u];
  const float b_n = bhh[1024 + u0 + u];
  float hprev = 0.0f;                // unit u's fp32 state (valid in piece==0 lane)

  #pragma unroll 1
  for (unsigned t = 0; t < 2048; ++t) {
    const int p = (int)(t & 1u);
    // gi prefetch for the cell lane (overlaps the poll)
    float gir = 0.f, giz = 0.f, gin = 0.f;
    if (piece == 0) {
      const float* gp = gi + (size_t)(b * 2048 + (int)t) * 1536 + u0 + u;
      gir = gp[0]; giz = gp[512]; gin = gp[1024];
    }
    // poll ONE packed word (tag==t => f16x2 valid), stage to LDS
    {
      const unsigned long long* pp = hbuf + ((size_t)p * 4 + b) * 256 + tid;
      unsigned long long w = __hip_atomic_load(pp, __ATOMIC_RELAXED, __HIP_MEMORY_SCOPE_AGENT);
      while ((unsigned)(w >> 32) != t)
        w = __hip_atomic_load(pp, __ATOMIC_RELAXED, __HIP_MEMORY_SCOPE_AGENT);
      hs2[p][(tid >> 5) * 36 + (tid & 31)] = (unsigned)w;
    }
    __syncthreads();
    // dots: 3 gates of unit u over this thread's k-piece
    const unsigned* hp = &hs2[p][piece * 36];
    float ar = 0.f, az = 0.f, an = 0.f;
    #pragma unroll
    for (int i = 0; i < 8; ++i) {
      uint4 h4 = *(const uint4*)(hp + 4 * i);
      ar = dot2f(wr0[4 * i + 0], h4.x, ar); ar = dot2f(wr0[4 * i + 1], h4.y, ar);
      ar = dot2f(wr0[4 * i + 2], h4.z, ar); ar = dot2f(wr0[4 * i + 3], h4.w, ar);
      az = dot2f(wr1[4 * i + 0], h4.x, az); az = dot2f(wr1[4 * i + 1], h4.y, az);
      az = dot2f(wr1[4 * i + 2], h4.z, az); az = dot2f(wr1[4 * i + 3], h4.w, az);
      an = dot2f(wr2[4 * i + 0], h4.x, an); an = dot2f(wr2[4 * i + 1], h4.y, an);
      an = dot2f(wr2[4 * i + 2], h4.z, an); an = dot2f(wr2[4 * i + 3], h4.w, an);
    }
    // reduce over the unit's 8 piece-lanes (lane bits 0..2)
    #pragma unroll
    for (int m = 1; m < 8; m <<= 1) {
      ar += __shfl_xor(ar, m);
      az += __shfl_xor(az, m);
      an += __shfl_xor(an, m);
    }
    // cell + publish in the piece==0 lane
    if (piece == 0) {
      float r  = sigmoidf_(gir + ar + b_r);
      float zg = sigmoidf_(giz + az + b_z);
      float n  = tanhf(gin + r * (an + b_n));
      float hnew = (1.0f - zg) * n + zg * hprev;
      hprev = hnew;
      hs[(size_t)(b * 2048 + (int)t) * 512 + u0 + u] = hnew;
      float hpart = __shfl_xor(hnew, 8);   // partner unit u^1 (lane ^8, also piece==0)
      if ((u & 1) == 0) {
        union { unsigned u32; _Float16 hh[2]; } pk;
        pk.hh[0] = (_Float16)hnew;   // unit u0+u   (even)
        pk.hh[1] = (_Float16)hpart;  // unit u0+u+1 (odd)
        unsigned long long wq = ((unsigned long long)(t + 1u) << 32) | (unsigned long long)pk.u32;
        __hip_atomic_store(hbuf + ((size_t)((t + 1u) & 1u) * 4 + b) * 256 + (u0 >> 1) + (u >> 1),
                           wq, __ATOMIC_RELAXED, __HIP_MEMORY_SCOPE_AGENT);
      }
    }
    // single barrier per step (top of next iteration) orders hs2 reuse.
  }
}

// ---------------- heads: oq, v_gain, u_gain, ff(cumsum), fb ----------------
__global__ __launch_bounds__(256) void k_heads(
    const float* __restrict__ hs,
    const float* __restrict__ Woq, const float* __restrict__ boq,
    const float* __restrict__ Wvg, const float* __restrict__ bvg,
    const float* __restrict__ Wug, const float* __restrict__ bug,
    const float* __restrict__ Wff, const float* __restrict__ bff,
    const float* __restrict__ Wfb, const float* __restrict__ bfb,
    float* __restrict__ out,
    float* __restrict__ oqw, float* __restrict__ vgw, float* __restrict__ ugw,
    float* __restrict__ ffw, float* __restrict__ fbw)
{
  int bf = blockIdx.x, tid = threadIdx.x;
  const float* h = hs + (size_t)bf * 512;
  float p[11];
  #pragma unroll
  for (int i = 0; i < 11; ++i) p[i] = 0.f;
  for (int k = tid; k < 512; k += 256) {
    float hv = h[k];
    p[0] = fmaf(Woq[k], hv, p[0]);
    p[1] = fmaf(Wvg[k], hv, p[1]);
    p[2] = fmaf(Wug[k], hv, p[2]);
    p[3] = fmaf(Wff[k], hv, p[3]);
    p[4] = fmaf(Wff[512 + k], hv, p[4]);
    p[5] = fmaf(Wff[1024 + k], hv, p[5]);
    p[6] = fmaf(Wff[1536 + k], hv, p[6]);
    p[7] = fmaf(Wfb[k], hv, p[7]);
    p[8] = fmaf(Wfb[512 + k], hv, p[8]);
    p[9] = fmaf(Wfb[1024 + k], hv, p[9]);
    p[10] = fmaf(Wfb[1536 + k], hv, p[10]);
  }
  #pragma unroll
  for (int i = 0; i < 11; ++i) {
    float v = p[i];
    #pragma unroll
    for (int m = 1; m < 64; m <<= 1) v += __shfl_xor(v, m);
    p[i] = v;
  }
  __shared__ float r4[4][11];
  if ((tid & 63) == 0) {
    int w = tid >> 6;
    #pragma unroll
    for (int i = 0; i < 11; ++i) r4[w][i] = p[i];
  }
  __syncthreads();
  if (tid == 0) {
    float s[11];
    #pragma unroll
    for (int i = 0; i < 11; ++i) s[i] = r4[0][i] + r4[1][i] + r4[2][i] + r4[3][i];
    float oqv = sigmoidf_(s[0] + boq[0]);
    float vg = softplusf(s[1] + bvg[0]);
    float ug = softplusf(s[2] + bug[0]);
    out[O1 + bf] = oqv; oqw[bf] = oqv;
    out[O2 + bf] = vg;  vgw[bf] = vg;
    out[O3 + bf] = ug;  ugw[bf] = ug;
    float run = 200.0f;
    #pragma unroll
    for (int j = 0; j < 4; ++j) {
      run += softplusf(s[3 + j] + bff[j]);
      out[O4 + (size_t)bf * 4 + j] = run; ffw[(size_t)bf * 4 + j] = run;
    }
    #pragma unroll
    for (int j = 0; j < 4; ++j) {
      float g = softplusf(s[7 + j] + bfb[j]) + 50.0f;
      out[O5 + (size_t)bf * 4 + j] = g; fbw[(size_t)bf * 4 + j] = g;
    }
  }
}

// ---------------- per-batch prefix scan of cycles -> start phase ----------------
__global__ __launch_bounds__(256) void k_scan(const float* __restrict__ f0, float* __restrict__ startw) {
  __shared__ float ts[256];
  int b = blockIdx.x, tid = threadIdx.x;
  const float CY = 256.0f / 24000.0f;
  float c[8], run = 0.f;
  int base = b * 2048 + tid * 8;
  #pragma unroll
  for (int j = 0; j < 8; ++j) { c[j] = run; run += f0[base + j] * CY; }
  ts[tid] = run;
  __syncthreads();
  for (int off = 1; off < 256; off <<= 1) {
    float v = (tid >= off) ? ts[tid - off] : 0.0f;
    __syncthreads();
    ts[tid] += v;
    __syncthreads();
  }
  float excl = (tid == 0) ? 0.0f : ts[tid - 1];
  #pragma unroll
  for (int j = 0; j < 8; ++j) {
    float st = excl + c[j];
    startw[base + j] = st - floorf(st);
  }
}

// ---------------- glottal source + excitation ----------------
__global__ __launch_bounds__(256) void k_excite(
    const float* __restrict__ f0, const float* __restrict__ noise,
    const float* __restrict__ startw, const float* __restrict__ oqw,
    const float* __restrict__ vgw, const float* __restrict__ ugw,
    float* __restrict__ exc)
{
  int bf = blockIdx.x, i = threadIdx.x;
  float st = startw[bf], f0v = f0[bf], oqv = oqw[bf], vg = vgw[bf], ug = ugw[bf];
  float total = st + f0v * ((float)i * (1.0f / 24000.0f));
  float phi = total - floorf(total);
  float peak = oqv * 0.66f;
  float rise = 0.5f * (1.0f - cosf(PI_F * phi / (peak + 1e-6f)));
  float fall = cosf(PI_F * (phi - peak) / (2.0f * (oqv - peak) + 1e-6f));
  float v = (phi < peak) ? rise : ((phi < oqv) ? fall : 0.0f);
  exc[(size_t)bf * 256 + i] = v * vg + noise[(size_t)bf * 256 + i] * ug;
}

// ---------------- formant IR generation + normalization (stored reversed) ----------------
__global__ __launch_bounds__(256) void k_ir(
    const float* __restrict__ ffw, const float* __restrict__ fbw,
    float* __restrict__ filtR)
{
  __shared__ float ffs[4], fbs[4], ssc[1], wmax[4];
  int bf = blockIdx.x, tid = threadIdx.x;
  if (tid < 4) { ffs[tid] = ffw[(size_t)bf * 4 + tid]; fbs[tid] = fbw[(size_t)bf * 4 + tid]; }
  __syncthreads();
  float vals[4];
  float am = 0.f;
  #pragma unroll
  for (int it = 0; it < 4; ++it) {
    int k = it * 256 + tid;
    float t = (float)k * (1.0f / 24000.0f);
    float s = 0.f;
    #pragma unroll
    for (int j = 0; j < 4; ++j)
      s += expf(-PI_F * fbs[j] * t) * sinf(TWO_PI_F * ffs[j] * t);
    vals[it] = s;
    am = fmaxf(am, fabsf(s));
  }
  #pragma unroll
  for (int m = 1; m < 64; m <<= 1) am = fmaxf(am, __shfl_xor(am, m));
  if ((tid & 63) == 0) wmax[tid >> 6] = am;
  __syncthreads();
  if (tid == 0) ssc[0] = fmaxf(fmaxf(wmax[0], wmax[1]), fmaxf(wmax[2], wmax[3])) + 1e-8f;
  __syncthreads();
  float inv = 1.0f / ssc[0];
  #pragma unroll
  for (int it = 0; it < 4; ++it) {
    int k = it * 256 + tid;
    filtR[(size_t)bf * 1024 + (1023 - k)] = vals[it] * inv;
  }
}

// ---------------- per-frame FIR conv (full) + overlap-add via atomics ----------------
__global__ __launch_bounds__(256) void k_conv(
    const float* __restrict__ exc, const float* __restrict__ filtR,
    float* __restrict__ audio)
{
  __shared__ float es[256];
  __shared__ float fp[1536];
  int bf = blockIdx.x, tid = threadIdx.x;
  int b = bf >> 11, f = bf & 2047;
  es[tid] = exc[(size_t)bf * 256 + tid];
  for (int i = tid; i < 1536; i += 256) {
    int j = i - 256;
    fp[i] = (j >= 0 && j < 1024) ? filtR[(size_t)bf * 1024 + j] : 0.0f;
  }
  __syncthreads();
  int n0 = tid * 5;
  float V0 = fp[n0 + 256], V1 = fp[n0 + 257], V2 = fp[n0 + 258], V3 = fp[n0 + 259], V4 = fp[n0 + 260];
  float a0 = 0.f, a1 = 0.f, a2 = 0.f, a3 = 0.f, a4 = 0.f;
  #pragma unroll 4
  for (int m = 0; m < 256; ++m) {
    float e = es[m];
    a0 = fmaf(e, V0, a0); a1 = fmaf(e, V1, a1); a2 = fmaf(e, V2, a2);
    a3 = fmaf(e, V3, a3); a4 = fmaf(e, V4, a4);
    V4 = V3; V3 = V2; V2 = V1; V1 = V0;
    V0 = fp[n0 + 255 - m];
  }
  float* arow = audio + (size_t)b * AROW + APAD + (size_t)f * 256;
  if (n0 + 0 < LL) atomicAdd(&arow[n0 + 0], a0);
  if (n0 + 1 < LL) atomicAdd(&arow[n0 + 1], a1);
  if (n0 + 2 < LL) atomicAdd(&arow[n0 + 2], a2);
  if (n0 + 3 < LL) atomicAdd(&arow[n0 + 3], a3);
  if (n0 + 4 < LL) atomicAdd(&arow[n0 + 4], a4);
}

// ---------------- pad reverb ir to 24064 with zeros ----------------
__global__ __launch_bounds__(256) void k_padir(const float* __restrict__ ir, float* __restrict__ irp) {
  int i = blockIdx.x * 256 + threadIdx.x;
  if (i < 24064) irp[i] = (i < REV) ? ir[i] : 0.0f;
}

// ---------------- reverb FIR v4: 8x8 tiles, explicit scalar registers ----------------
__global__ __launch_bounds__(256) void k_reverb(
    const float* __restrict__ audio, const float* __restrict__ irp,
    const float* __restrict__ wetl, float* __restrict__ out)
{
  __shared__ float as_[2592];   // 2304 window, idx -> idx + 4*(idx>>5)
  int tb = blockIdx.x, b = blockIdx.y, tid = threadIdx.x;
  int tbase = tb * 2048;
  const float* arow = audio + (size_t)b * AROW;
  float acc0=0.f,acc1=0.f,acc2=0.f,acc3=0.f,acc4=0.f,acc5=0.f,acc6=0.f,acc7=0.f;

  for (int c = 0; c < 94; ++c) {
    __syncthreads();
    int B0 = APAD + tbase - c * 256 - 256;   // >= 0 always
    for (int i = tid; i < 2304; i += 256) {
      int g = B0 + i;
      float v = (g < (int)AROW) ? arow[g] : 0.0f;
      as_[i + 4 * (i >> 5)] = v;
    }
    __syncthreads();
    const float* irc = irp + c * 256;        // uniform -> scalar loads
    int W = 256 + 8 * tid;
    float4 A  = *(const float4*)&as_[W + 4 * (W >> 5)];
    int wi = W + 4;
    float4 Bv = *(const float4*)&as_[wi + 4 * (wi >> 5)];
    #pragma unroll 1
    for (int m = 0; m < 32; ++m) {
      int x0 = W - 8, x1 = W - 4;
      float4 C = *(const float4*)&as_[x0 + 4 * (x0 >> 5)];
      float4 D = *(const float4*)&as_[x1 + 4 * (x1 >> 5)];
      float e1=C.y,e2=C.z,e3=C.w,e4=D.x,e5=D.y,e6=D.z,e7=D.w,
            e8=A.x,e9=A.y,e10=A.z,e11=A.w,e12=Bv.x,e13=Bv.y,e14=Bv.z,e15=Bv.w;
#define RVT(s, E0,E1,E2,E3,E4,E5,E6,E7) { float w_ = irc[8*m+(s)]; \
      acc0=fmaf(w_,E0,acc0); acc1=fmaf(w_,E1,acc1); acc2=fmaf(w_,E2,acc2); acc3=fmaf(w_,E3,acc3); \
      acc4=fmaf(w_,E4,acc4); acc5=fmaf(w_,E5,acc5); acc6=fmaf(w_,E6,acc6); acc7=fmaf(w_,E7,acc7); }
      RVT(0, e8,e9,e10,e11,e12,e13,e14,e15)
      RVT(1, e7,e8,e9,e10,e11,e12,e13,e14)
      RVT(2, e6,e7,e8,e9,e10,e11,e12,e13)
      RVT(3, e5,e6,e7,e8,e9,e10,e11,e12)
      RVT(4, e4,e5,e6,e7,e8,e9,e10,e11)
      RVT(5, e3,e4,e5,e6,e7,e8,e9,e10)
      RVT(6, e2,e3,e4,e5,e6,e7,e8,e9)
      RVT(7, e1,e2,e3,e4,e5,e6,e7,e8)
#undef RVT
      A = C; Bv = D; W -= 8;
    }
  }
  float wet = sigmoidf_(wetl[0]);
  float accs[8] = {acc0,acc1,acc2,acc3,acc4,acc5,acc6,acc7};
  #pragma unroll
  for (int j = 0; j < 8; ++j) {
    long t = (long)tbase + 8 * tid + j;
    if (t < (long)TOT) {
      float av = arow[APAD + t];
      out[(size_t)b * TOT + t] = (1.0f - wet) * av + wet * accs[j];
    }
  }
}

// ---------------- launch ----------------
extern "C" void kernel_launch(void* const* d_in, const int* in_sizes, int n_in,
                              void* d_out, int out_size, void* d_ws, size_t ws_size,
                              hipStream_t stream) {
  const float* f0       = (const float*)d_in[0];
  const float* loud     = (const float*)d_in[1];
  const float* gender   = (const float*)d_in[2];
  const float* age      = (const float*)d_in[3];
  const float* z        = (const float*)d_in[4];
  const float* noise    = (const float*)d_in[5];
  const float* W_in     = (const float*)d_in[6];
  const float* b_in     = (const float*)d_in[7];
  const float* W_ih     = (const float*)d_in[8];
  const float* W_hh     = (const float*)d_in[9];
  const float* b_ih     = (const float*)d_in[10];
  const float* b_hh     = (const float*)d_in[11];
  const float* W_oq     = (const float*)d_in[12];
  const float* b_oq     = (const float*)d_in[13];
  const float* W_vg     = (const float*)d_in[14];
  const float* b_vg     = (const float*)d_in[15];
  const float* W_ug     = (const float*)d_in[16];
  const float* b_ug     = (const float*)d_in[17];
  const float* W_ff     = (const float*)d_in[18];
  const float* b_ff     = (const float*)d_in[19];
  const float* W_fb     = (const float*)d_in[20];
  const float* b_fb     = (const float*)d_in[21];
  const float* rev_ir   = (const float*)d_in[22];
  const float* wet_l    = (const float*)d_in[23];

  float* out = (float*)d_out;
  char* ws = (char*)d_ws;
  float* x      = (float*)(ws + OFF_X);
  float* gi     = (float*)(ws + OFF_GI);
  float* hs     = (float*)(ws + OFF_HS);
  float* filtR  = (float*)(ws + OFF_FILTR);
  float* oqw    = (float*)(ws + OFF_OQ);
  float* vgw    = (float*)(ws + OFF_VG);
  float* ugw    = (float*)(ws + OFF_UG);
  float* ffw    = (float*)(ws + OFF_FFW);
  float* fbw    = (float*)(ws + OFF_FBW);
  float* startw = (float*)(ws + OFF_START);
  float* f0m    = (float*)(ws + OFF_F0M);
  unsigned long long* hbuf = (unsigned long long*)(ws + OFF_HBUF);
  float* exc    = (float*)(ws + OFF_EXC);
  float* irp    = (float*)(ws + OFF_IRP);
  float* audio  = (float*)(ws + OFF_AUDIO);

  // zero tagged h double-buffer (16KB, overlays ffw until k_heads) + audio acc
  hipMemsetAsync(ws + OFF_HBUF, 0, 16384, stream);
  hipMemsetAsync(ws + OFF_AUDIO, 0, (size_t)4 * AROW * 4, stream);

  k_f0mean<<<4, 256, 0, stream>>>(f0, f0m);
  k_inproj<<<512, 256, 0, stream>>>(f0, loud, gender, age, z, f0m, W_in, b_in, x);
  k_gemm_gi<<<dim3(24, 128), 256, 0, stream>>>(x, W_ih, b_ih, gi);
  k_gru<<<64, 256, 0, stream>>>(W_hh, b_hh, gi, hs, hbuf);
  k_heads<<<8192, 256, 0, stream>>>(hs, W_oq, b_oq, W_vg, b_vg, W_ug, b_ug,
                                    W_ff, b_ff, W_fb, b_fb, out, oqw, vgw, ugw, ffw, fbw);
  k_scan<<<4, 256, 0, stream>>>(f0, startw);
  k_excite<<<8192, 256, 0, stream>>>(f0, noise, startw, oqw, vgw, ugw, exc);
  k_ir<<<8192, 256, 0, stream>>>(ffw, fbw, filtR);
  k_conv<<<8192, 256, 0, stream>>>(exc, filtR, audio);
  k_padir<<<94, 256, 0, stream>>>(rev_ir, irp);   // gi region dead after k_gru
  k_reverb<<<dim3(257, 4), 256, 0, stream>>>(audio, irp, wet_l, out);
}

// Round 10
// 5662.894 us; speedup vs baseline: 1.1344x; 1.1344x over previous
//
#include <hip/hip_runtime.h>
#include <hip/hip_bf16.h>
#include <math.h>

// ---------------- constants ----------------
#define PI_F 3.14159265358979323846f
#define TWO_PI_F 6.283185307179586f

constexpr int BB = 4;            // batch
constexpr int FF_ = 2048;        // frames
constexpr int RC = 512;          // rnn channels
constexpr int HOP = 256;
constexpr int KK = 1024;         // FIR len
constexpr int LL = HOP + KK - 1; // 1279
constexpr size_t TOT = 525311;   // (F-1)*HOP + L
constexpr int APAD = 24064;      // zero pad in front of audio rows (>= REV-1, mult of 64)
constexpr size_t AROW = 549376;  // APAD + 525312
constexpr int REV = 24000;

// output offsets (floats)
constexpr size_t O1 = 2101244;   // oq
constexpr size_t O2 = 2109436;   // v_gain
constexpr size_t O3 = 2117628;   // u_gain
constexpr size_t O4 = 2125820;   // ff
constexpr size_t O5 = 2158588;   // fb

// workspace offsets (bytes)
constexpr size_t OFF_X      = 0;                 // 8192*512*4
constexpr size_t OFF_GI     = 16777216;          // 8192*1536*4
constexpr size_t OFF_HS     = 67108864;          // 8192*512*4
constexpr size_t OFF_FILTR  = 0;                 // 8192*1024*4 (overlays X/GI, dead by then)
constexpr size_t OFF_OQ     = 83886080;
constexpr size_t OFF_VG     = 83918848;
constexpr size_t OFF_UG     = 83951616;
constexpr size_t OFF_FFW    = 83984384;          // also hbuf (16KB) during k_gru; ffw written after
constexpr size_t OFF_FBW    = 84115456;
constexpr size_t OFF_START  = 84246528;
constexpr size_t OFF_F0M    = 84279296;
constexpr size_t OFF_EXC    = 84296192;          // 8192*256*4
constexpr size_t OFF_IRP    = 50331648;          // padded reverb ir — in gi dead-zone, used after k_gru
constexpr size_t OFF_AUDIO  = 92684800;          // 4*549376*4

constexpr size_t OFF_HBUF   = OFF_FFW;           // 2 slots x 4 batch x 256 words x 8B = 16KB

__device__ __forceinline__ float softplusf(float x) {
  return x > 20.0f ? x : log1pf(expf(x));
}
__device__ __forceinline__ float sigmoidf_(float x) {
  return 1.0f / (1.0f + expf(-x));
}

typedef _Float16 half2v __attribute__((ext_vector_type(2)));
typedef _Float16 f16x8 __attribute__((ext_vector_type(8)));
typedef float f32x4 __attribute__((ext_vector_type(4)));

__device__ __forceinline__ float dot2f(unsigned wa, unsigned hb, float acc) {
#if __has_builtin(__builtin_amdgcn_fdot2)
  union { unsigned u; half2v h; } A, B;
  A.u = wa; B.u = hb;
  return __builtin_amdgcn_fdot2(A.h, B.h, acc, false);
#else
  union { unsigned u; _Float16 h[2]; } A, B;
  A.u = wa; B.u = hb;
  return fmaf((float)A.h[0], (float)B.h[0], fmaf((float)A.h[1], (float)B.h[1], acc));
#endif
}

// ---------------- f0 mean per batch ----------------
__global__ __launch_bounds__(256) void k_f0mean(const float* __restrict__ f0, float* __restrict__ f0m) {
  int b = blockIdx.x, tid = threadIdx.x;
  float s = 0.f;
  for (int t = tid; t < FF_; t += 256) s += f0[b*FF_ + t];
  #pragma unroll
  for (int m = 1; m < 64; m <<= 1) s += __shfl_xor(s, m);
  __shared__ float ws4[4];
  if ((tid & 63) == 0) ws4[tid >> 6] = s;
  __syncthreads();
  if (tid == 0) f0m[b] = (ws4[0] + ws4[1] + ws4[2] + ws4[3]) * (1.0f / 2048.0f);
}

// ---------------- input projection: x = relu(concat @ W_in^T + b_in) ----------------
__global__ __launch_bounds__(256) void k_inproj(
    const float* __restrict__ f0, const float* __restrict__ loud,
    const float* __restrict__ gender, const float* __restrict__ age,
    const float* __restrict__ z, const float* __restrict__ f0m,
    const float* __restrict__ Win, const float* __restrict__ bin,
    float* __restrict__ x)
{
  __shared__ float inp[16 * 28];
  int r0 = blockIdx.x * 16;   // bf base
  int tid = threadIdx.x;
  for (int i = tid; i < 16 * 28; i += 256) {
    int r = i / 28, c = i % 28;
    int bf = r0 + r, b = bf >> 11;
    float v;
    if (c == 0)       v = f0[bf] - f0m[b];
    else if (c == 1)  v = loud[bf];
    else if (c < 4)   v = gender[(size_t)bf*2 + (c - 2)];
    else if (c < 12)  v = age[(size_t)bf*8 + (c - 4)];
    else              v = z[(size_t)bf*16 + (c - 12)];
    inp[i] = v;
  }
  __syncthreads();
  for (int o = tid; o < 16 * 512; o += 256) {
    int r = o >> 9, j = o & 511;
    const float* w = Win + j * 28;
    const float* ip = inp + r * 28;
    float a = bin[j];
    #pragma unroll
    for (int c2 = 0; c2 < 28; ++c2) a = fmaf(w[c2], ip[c2], a);
    x[(size_t)(r0 + r) * 512 + j] = fmaxf(a, 0.0f);
  }
}

// ---------------- GEMM v2 (MFMA f16): gi = x @ W_ih^T + b_ih ----------------
// M=8192, N=1536, K=512. 64x64 tile/WG, 4 waves x (2x2 of 16x16 subtiles),
// K-chunks of 32 staged in LDS as f16 pairs. Fragment layouts (HW-verified
// per guide): A[m=lane&15][k=quad*8+j]; B[k=quad*8+j][n=lane&15];
// D col=lane&15, row=quad*4+reg.
__global__ __launch_bounds__(256) void k_gemm_gi(
    const float* __restrict__ A, const float* __restrict__ Bw,
    const float* __restrict__ bias, float* __restrict__ C)
{
  __shared__ unsigned As[64 * 20];  // f16-pair dwords, row stride 20 (16B-aligned rows)
  __shared__ unsigned Bs[64 * 20];
  int tid = threadIdx.x;
  int n0 = blockIdx.x * 64, m0 = blockIdx.y * 64;
  const int w = tid >> 6;           // wave 0..3
  const int lane = tid & 63;
  const int mrow0 = (w >> 1) * 32;  // wave row base within tile
  const int ncol0 = (w & 1) * 32;   // wave col base within tile
  const int lm = lane & 15;
  const int quad = lane >> 4;

  f32x4 acc00 = {0.f,0.f,0.f,0.f}, acc01 = {0.f,0.f,0.f,0.f};
  f32x4 acc10 = {0.f,0.f,0.f,0.f}, acc11 = {0.f,0.f,0.f,0.f};

  for (int k0 = 0; k0 < 512; k0 += 32) {
    __syncthreads();
    // stage A,B chunk: 64 rows x 16 f16-pair dwords each
    for (int i = tid; i < 1024; i += 256) {
      int r = i >> 4, d = i & 15;
      float2 av = *(const float2*)(A + (size_t)(m0 + r) * 512 + k0 + 2 * d);
      float2 bv = *(const float2*)(Bw + (size_t)(n0 + r) * 512 + k0 + 2 * d);
      union { unsigned u32; _Float16 h[2]; } pa, pb;
      pa.h[0] = (_Float16)av.x; pa.h[1] = (_Float16)av.y;
      pb.h[0] = (_Float16)bv.x; pb.h[1] = (_Float16)bv.y;
      As[r * 20 + d] = pa.u32;
      Bs[r * 20 + d] = pb.u32;
    }
    __syncthreads();
    union { uint4 u; f16x8 h; } a0, a1, b0, b1;
    a0.u = *(const uint4*)&As[(mrow0 + lm) * 20 + quad * 4];
    a1.u = *(const uint4*)&As[(mrow0 + 16 + lm) * 20 + quad * 4];
    b0.u = *(const uint4*)&Bs[(ncol0 + lm) * 20 + quad * 4];
    b1.u = *(const uint4*)&Bs[(ncol0 + 16 + lm) * 20 + quad * 4];
    acc00 = __builtin_amdgcn_mfma_f32_16x16x32_f16(a0.h, b0.h, acc00, 0, 0, 0);
    acc01 = __builtin_amdgcn_mfma_f32_16x16x32_f16(a0.h, b1.h, acc01, 0, 0, 0);
    acc10 = __builtin_amdgcn_mfma_f32_16x16x32_f16(a1.h, b0.h, acc10, 0, 0, 0);
    acc11 = __builtin_amdgcn_mfma_f32_16x16x32_f16(a1.h, b1.h, acc11, 0, 0, 0);
  }
  // epilogue: D col=lane&15, row=quad*4+reg
  #pragma unroll
  for (int sm = 0; sm < 2; ++sm) {
    #pragma unroll
    for (int sn = 0; sn < 2; ++sn) {
      const f32x4& ac = sm ? (sn ? acc11 : acc10) : (sn ? acc01 : acc00);
      int col = n0 + ncol0 + sn * 16 + lm;
      float bb = bias[col];
      #pragma unroll
      for (int rg = 0; rg < 4; ++rg) {
        int row = m0 + mrow0 + sm * 16 + quad * 4 + rg;
        C[(size_t)row * 1536 + col] = ac[rg] + bb;
      }
    }
  }
}

// ---------------- persistent GRU v7: 2-row h reuse, 128 WGs ----------------
// (round-8 winner, reverted verbatim: 3.23 ms)
__global__ __launch_bounds__(256, 1) void k_gru(
    const float* __restrict__ Whh, const float* __restrict__ bhh,
    const float* __restrict__ gi, float* __restrict__ hs,
    unsigned long long* hbuf)
{
  __shared__ unsigned hs2[2][292];   // 8 pieces x 36-dword stride per parity
  __shared__ float red[2][384];      // [row*8 + piece]
  __shared__ float bhh_s[48];

  const int tid = threadIdx.x;
  const int b   = blockIdx.x & 3;    // batch / group
  const int wgi = blockIdx.x >> 2;   // 0..31
  const int u0  = wgi * 16;
  const int piece = tid & 7;         // dot threads (tid<192)
  const int rp    = tid >> 3;        // row pair 0..23

  // per-thread weight registers: rows 2rp, 2rp+1 over k-piece [64*piece, +64)
  unsigned w0r[32], w1r[32];
  if (tid < 192) {
    int r0 = 2 * rp, r1 = 2 * rp + 1;      // row = g3*16 + u
    const float* s0 = Whh + (size_t)((r0 >> 4) * 512 + u0 + (r0 & 15)) * 512 + piece * 64;
    const float* s1 = Whh + (size_t)((r1 >> 4) * 512 + u0 + (r1 & 15)) * 512 + piece * 64;
    #pragma unroll
    for (int j = 0; j < 32; ++j) {
      float2 a = *(const float2*)(s0 + 2 * j);
      float2 c = *(const float2*)(s1 + 2 * j);
      union { unsigned u32; _Float16 hh[2]; } ca, cb;
      ca.hh[0] = (_Float16)a.x; ca.hh[1] = (_Float16)a.y;
      cb.hh[0] = (_Float16)c.x; cb.hh[1] = (_Float16)c.y;
      w0r[j] = ca.u32; w1r[j] = cb.u32;
    }
  } else {
    #pragma unroll
    for (int j = 0; j < 32; ++j) { w0r[j] = 0u; w1r[j] = 0u; }
  }
  if (tid < 48) bhh_s[tid] = bhh[(tid >> 4) * 512 + u0 + (tid & 15)];
  __syncthreads();

  float hprev = 0.0f;                // own unit's fp32 state (lanes<16)

  #pragma unroll 1
  for (unsigned t = 0; t < 2048; ++t) {
    const int p = (int)(t & 1u);
    // gi prefetch for the cell (overlaps the poll)
    float gir = 0.f, giz = 0.f, gin = 0.f;
    if (tid < 16) {
      const float* gp = gi + (size_t)(b * 2048 + (int)t) * 1536 + u0 + tid;
      gir = gp[0]; giz = gp[512]; gin = gp[1024];
    }
    // poll ONE packed word (tag==t => f16x2 valid), stage to LDS
    {
      const unsigned long long* pp = hbuf + ((size_t)p * 4 + b) * 256 + tid;
      unsigned long long w = __hip_atomic_load(pp, __ATOMIC_RELAXED, __HIP_MEMORY_SCOPE_AGENT);
      while ((unsigned)(w >> 32) != t)
        w = __hip_atomic_load(pp, __ATOMIC_RELAXED, __HIP_MEMORY_SCOPE_AGENT);
      hs2[p][(tid >> 5) * 36 + (tid & 31)] = (unsigned)w;
    }
    __syncthreads();
    // partial dots: 48 rows x 8 k-pieces, 2 rows per thread reuse each h4
    if (tid < 192) {
      const unsigned* hp = &hs2[p][piece * 36];
      float a00 = 0.f, a01 = 0.f, a10 = 0.f, a11 = 0.f;
      #pragma unroll
      for (int i = 0; i < 8; ++i) {
        uint4 h4 = *(const uint4*)(hp + 4 * i);
        a00 = dot2f(w0r[4 * i + 0], h4.x, a00);
        a01 = dot2f(w0r[4 * i + 1], h4.y, a01);
        a00 = dot2f(w0r[4 * i + 2], h4.z, a00);
        a01 = dot2f(w0r[4 * i + 3], h4.w, a01);
        a10 = dot2f(w1r[4 * i + 0], h4.x, a10);
        a11 = dot2f(w1r[4 * i + 1], h4.y, a11);
        a10 = dot2f(w1r[4 * i + 2], h4.z, a10);
        a11 = dot2f(w1r[4 * i + 3], h4.w, a11);
      }
      red[p][(2 * rp) * 8 + piece]     = a00 + a01;
      red[p][(2 * rp + 1) * 8 + piece] = a10 + a11;
    }
    __syncthreads();
    // cell update + publish (lanes 0..15)
    if (tid < 16) {
      const float* r0p = &red[p][tid * 8];
      const float* r1p = &red[p][(16 + tid) * 8];
      const float* r2p = &red[p][(32 + tid) * 8];
      float4 q0 = *(const float4*)r0p, q1 = *(const float4*)(r0p + 4);
      float4 z0 = *(const float4*)r1p, z1 = *(const float4*)(r1p + 4);
      float4 n0 = *(const float4*)r2p, n1 = *(const float4*)(r2p + 4);
      float ghr = ((q0.x + q0.y) + (q0.z + q0.w)) + ((q1.x + q1.y) + (q1.z + q1.w)) + bhh_s[tid];
      float ghz = ((z0.x + z0.y) + (z0.z + z0.w)) + ((z1.x + z1.y) + (z1.z + z1.w)) + bhh_s[16 + tid];
      float ghn = ((n0.x + n0.y) + (n0.z + n0.w)) + ((n1.x + n1.y) + (n1.z + n1.w)) + bhh_s[32 + tid];
      float r  = sigmoidf_(gir + ghr);
      float zg = sigmoidf_(giz + ghz);
      float n  = tanhf(gin + r * ghn);
      float hnew = (1.0f - zg) * n + zg * hprev;
      hprev = hnew;
      hs[(size_t)(b * 2048 + (int)t) * 512 + u0 + tid] = hnew;
      float hpart = __shfl_xor(hnew, 1);
      if ((tid & 1) == 0) {
        union { unsigned u32; _Float16 hh[2]; } pk;
        pk.hh[0] = (_Float16)hnew;   // unit u0+tid   (even)
        pk.hh[1] = (_Float16)hpart;  // unit u0+tid+1 (odd)
        unsigned long long wq = ((unsigned long long)(t + 1u) << 32) | (unsigned long long)pk.u32;
        __hip_atomic_store(hbuf + ((size_t)((t + 1u) & 1u) * 4 + b) * 256 + (u0 >> 1) + (tid >> 1),
                           wq, __ATOMIC_RELAXED, __HIP_MEMORY_SCOPE_AGENT);
      }
    }
    // no trailing barrier: parity double-buffering + tag induction gate reuse.
  }
}

// ---------------- heads: oq, v_gain, u_gain, ff(cumsum), fb ----------------
__global__ __launch_bounds__(256) void k_heads(
    const float* __restrict__ hs,
    const float* __restrict__ Woq, const float* __restrict__ boq,
    const float* __restrict__ Wvg, const float* __restrict__ bvg,
    const float* __restrict__ Wug, const float* __restrict__ bug,
    const float* __restrict__ Wff, const float* __restrict__ bff,
    const float* __restrict__ Wfb, const float* __restrict__ bfb,
    float* __restrict__ out,
    float* __restrict__ oqw, float* __restrict__ vgw, float* __restrict__ ugw,
    float* __restrict__ ffw, float* __restrict__ fbw)
{
  int bf = blockIdx.x, tid = threadIdx.x;
  const float* h = hs + (size_t)bf * 512;
  float p[11];
  #pragma unroll
  for (int i = 0; i < 11; ++i) p[i] = 0.f;
  for (int k = tid; k < 512; k += 256) {
    float hv = h[k];
    p[0] = fmaf(Woq[k], hv, p[0]);
    p[1] = fmaf(Wvg[k], hv, p[1]);
    p[2] = fmaf(Wug[k], hv, p[2]);
    p[3] = fmaf(Wff[k], hv, p[3]);
    p[4] = fmaf(Wff[512 + k], hv, p[4]);
    p[5] = fmaf(Wff[1024 + k], hv, p[5]);
    p[6] = fmaf(Wff[1536 + k], hv, p[6]);
    p[7] = fmaf(Wfb[k], hv, p[7]);
    p[8] = fmaf(Wfb[512 + k], hv, p[8]);
    p[9] = fmaf(Wfb[1024 + k], hv, p[9]);
    p[10] = fmaf(Wfb[1536 + k], hv, p[10]);
  }
  #pragma unroll
  for (int i = 0; i < 11; ++i) {
    float v = p[i];
    #pragma unroll
    for (int m = 1; m < 64; m <<= 1) v += __shfl_xor(v, m);
    p[i] = v;
  }
  __shared__ float r4[4][11];
  if ((tid & 63) == 0) {
    int w = tid >> 6;
    #pragma unroll
    for (int i = 0; i < 11; ++i) r4[w][i] = p[i];
  }
  __syncthreads();
  if (tid == 0) {
    float s[11];
    #pragma unroll
    for (int i = 0; i < 11; ++i) s[i] = r4[0][i] + r4[1][i] + r4[2][i] + r4[3][i];
    float oqv = sigmoidf_(s[0] + boq[0]);
    float vg = softplusf(s[1] + bvg[0]);
    float ug = softplusf(s[2] + bug[0]);
    out[O1 + bf] = oqv; oqw[bf] = oqv;
    out[O2 + bf] = vg;  vgw[bf] = vg;
    out[O3 + bf] = ug;  ugw[bf] = ug;
    float run = 200.0f;
    #pragma unroll
    for (int j = 0; j < 4; ++j) {
      run += softplusf(s[3 + j] + bff[j]);
      out[O4 + (size_t)bf * 4 + j] = run; ffw[(size_t)bf * 4 + j] = run;
    }
    #pragma unroll
    for (int j = 0; j < 4; ++j) {
      float g = softplusf(s[7 + j] + bfb[j]) + 50.0f;
      out[O5 + (size_t)bf * 4 + j] = g; fbw[(size_t)bf * 4 + j] = g;
    }
  }
}

// ---------------- per-batch prefix scan of cycles -> start phase ----------------
__global__ __launch_bounds__(256) void k_scan(const float* __restrict__ f0, float* __restrict__ startw) {
  __shared__ float ts[256];
  int b = blockIdx.x, tid = threadIdx.x;
  const float CY = 256.0f / 24000.0f;
  float c[8], run = 0.f;
  int base = b * 2048 + tid * 8;
  #pragma unroll
  for (int j = 0; j < 8; ++j) { c[j] = run; run += f0[base + j] * CY; }
  ts[tid] = run;
  __syncthreads();
  for (int off = 1; off < 256; off <<= 1) {
    float v = (tid >= off) ? ts[tid - off] : 0.0f;
    __syncthreads();
    ts[tid] += v;
    __syncthreads();
  }
  float excl = (tid == 0) ? 0.0f : ts[tid - 1];
  #pragma unroll
  for (int j = 0; j < 8; ++j) {
    float st = excl + c[j];
    startw[base + j] = st - floorf(st);
  }
}

// ---------------- glottal source + excitation ----------------
__global__ __launch_bounds__(256) void k_excite(
    const float* __restrict__ f0, const float* __restrict__ noise,
    const float* __restrict__ startw, const float* __restrict__ oqw,
    const float* __restrict__ vgw, const float* __restrict__ ugw,
    float* __restrict__ exc)
{
  int bf = blockIdx.x, i = threadIdx.x;
  float st = startw[bf], f0v = f0[bf], oqv = oqw[bf], vg = vgw[bf], ug = ugw[bf];
  float total = st + f0v * ((float)i * (1.0f / 24000.0f));
  float phi = total - floorf(total);
  float peak = oqv * 0.66f;
  float rise = 0.5f * (1.0f - cosf(PI_F * phi / (peak + 1e-6f)));
  float fall = cosf(PI_F * (phi - peak) / (2.0f * (oqv - peak) + 1e-6f));
  float v = (phi < peak) ? rise : ((phi < oqv) ? fall : 0.0f);
  exc[(size_t)bf * 256 + i] = v * vg + noise[(size_t)bf * 256 + i] * ug;
}

// ---------------- formant IR generation + normalization (stored reversed) ----------------
__global__ __launch_bounds__(256) void k_ir(
    const float* __restrict__ ffw, const float* __restrict__ fbw,
    float* __restrict__ filtR)
{
  __shared__ float ffs[4], fbs[4], ssc[1], wmax[4];
  int bf = blockIdx.x, tid = threadIdx.x;
  if (tid < 4) { ffs[tid] = ffw[(size_t)bf * 4 + tid]; fbs[tid] = fbw[(size_t)bf * 4 + tid]; }
  __syncthreads();
  float vals[4];
  float am = 0.f;
  #pragma unroll
  for (int it = 0; it < 4; ++it) {
    int k = it * 256 + tid;
    float t = (float)k * (1.0f / 24000.0f);
    float s = 0.f;
    #pragma unroll
    for (int j = 0; j < 4; ++j)
      s += expf(-PI_F * fbs[j] * t) * sinf(TWO_PI_F * ffs[j] * t);
    vals[it] = s;
    am = fmaxf(am, fabsf(s));
  }
  #pragma unroll
  for (int m = 1; m < 64; m <<= 1) am = fmaxf(am, __shfl_xor(am, m));
  if ((tid & 63) == 0) wmax[tid >> 6] = am;
  __syncthreads();
  if (tid == 0) ssc[0] = fmaxf(fmaxf(wmax[0], wmax[1]), fmaxf(wmax[2], wmax[3])) + 1e-8f;
  __syncthreads();
  float inv = 1.0f / ssc[0];
  #pragma unroll
  for (int it = 0; it < 4; ++it) {
    int k = it * 256 + tid;
    filtR[(size_t)bf * 1024 + (1023 - k)] = vals[it] * inv;
  }
}

// ---------------- per-frame FIR conv (full) + overlap-add via atomics ----------------
__global__ __launch_bounds__(256) void k_conv(
    const float* __restrict__ exc, const float* __restrict__ filtR,
    float* __restrict__ audio)
{
  __shared__ float es[256];
  __shared__ float fp[1536];
  int bf = blockIdx.x, tid = threadIdx.x;
  int b = bf >> 11, f = bf & 2047;
  es[tid] = exc[(size_t)bf * 256 + tid];
  for (int i = tid; i < 1536; i += 256) {
    int j = i - 256;
    fp[i] = (j >= 0 && j < 1024) ? filtR[(size_t)bf * 1024 + j] : 0.0f;
  }
  __syncthreads();
  int n0 = tid * 5;
  float V0 = fp[n0 + 256], V1 = fp[n0 + 257], V2 = fp[n0 + 258], V3 = fp[n0 + 259], V4 = fp[n0 + 260];
  float a0 = 0.f, a1 = 0.f, a2 = 0.f, a3 = 0.f, a4 = 0.f;
  #pragma unroll 4
  for (int m = 0; m < 256; ++m) {
    float e = es[m];
    a0 = fmaf(e, V0, a0); a1 = fmaf(e, V1, a1); a2 = fmaf(e, V2, a2);
    a3 = fmaf(e, V3, a3); a4 = fmaf(e, V4, a4);
    V4 = V3; V3 = V2; V2 = V1; V1 = V0;
    V0 = fp[n0 + 255 - m];
  }
  float* arow = audio + (size_t)b * AROW + APAD + (size_t)f * 256;
  if (n0 + 0 < LL) atomicAdd(&arow[n0 + 0], a0);
  if (n0 + 1 < LL) atomicAdd(&arow[n0 + 1], a1);
  if (n0 + 2 < LL) atomicAdd(&arow[n0 + 2], a2);
  if (n0 + 3 < LL) atomicAdd(&arow[n0 + 3], a3);
  if (n0 + 4 < LL) atomicAdd(&arow[n0 + 4], a4);
}

// ---------------- pad reverb ir to 24064 with zeros ----------------
__global__ __launch_bounds__(256) void k_padir(const float* __restrict__ ir, float* __restrict__ irp) {
  int i = blockIdx.x * 256 + threadIdx.x;
  if (i < 24064) irp[i] = (i < REV) ? ir[i] : 0.0f;
}

// ---------------- reverb FIR v4: 8x8 tiles, explicit scalar registers ----------------
__global__ __launch_bounds__(256) void k_reverb(
    const float* __restrict__ audio, const float* __restrict__ irp,
    const float* __restrict__ wetl, float* __restrict__ out)
{
  __shared__ float as_[2592];   // 2304 window, idx -> idx + 4*(idx>>5)
  int tb = blockIdx.x, b = blockIdx.y, tid = threadIdx.x;
  int tbase = tb * 2048;
  const float* arow = audio + (size_t)b * AROW;
  float acc0=0.f,acc1=0.f,acc2=0.f,acc3=0.f,acc4=0.f,acc5=0.f,acc6=0.f,acc7=0.f;

  for (int c = 0; c < 94; ++c) {
    __syncthreads();
    int B0 = APAD + tbase - c * 256 - 256;   // >= 0 always
    for (int i = tid; i < 2304; i += 256) {
      int g = B0 + i;
      float v = (g < (int)AROW) ? arow[g] : 0.0f;
      as_[i + 4 * (i >> 5)] = v;
    }
    __syncthreads();
    const float* irc = irp + c * 256;        // uniform -> scalar loads
    int W = 256 + 8 * tid;
    float4 A  = *(const float4*)&as_[W + 4 * (W >> 5)];
    int wi = W + 4;
    float4 Bv = *(const float4*)&as_[wi + 4 * (wi >> 5)];
    #pragma unroll 1
    for (int m = 0; m < 32; ++m) {
      int x0 = W - 8, x1 = W - 4;
      float4 C = *(const float4*)&as_[x0 + 4 * (x0 >> 5)];
      float4 D = *(const float4*)&as_[x1 + 4 * (x1 >> 5)];
      float e1=C.y,e2=C.z,e3=C.w,e4=D.x,e5=D.y,e6=D.z,e7=D.w,
            e8=A.x,e9=A.y,e10=A.z,e11=A.w,e12=Bv.x,e13=Bv.y,e14=Bv.z,e15=Bv.w;
#define RVT(s, E0,E1,E2,E3,E4,E5,E6,E7) { float w_ = irc[8*m+(s)]; \
      acc0=fmaf(w_,E0,acc0); acc1=fmaf(w_,E1,acc1); acc2=fmaf(w_,E2,acc2); acc3=fmaf(w_,E3,acc3); \
      acc4=fmaf(w_,E4,acc4); acc5=fmaf(w_,E5,acc5); acc6=fmaf(w_,E6,acc6); acc7=fmaf(w_,E7,acc7); }
      RVT(0, e8,e9,e10,e11,e12,e13,e14,e15)
      RVT(1, e7,e8,e9,e10,e11,e12,e13,e14)
      RVT(2, e6,e7,e8,e9,e10,e11,e12,e13)
      RVT(3, e5,e6,e7,e8,e9,e10,e11,e12)
      RVT(4, e4,e5,e6,e7,e8,e9,e10,e11)
      RVT(5, e3,e4,e5,e6,e7,e8,e9,e10)
      RVT(6, e2,e3,e4,e5,e6,e7,e8,e9)
      RVT(7, e1,e2,e3,e4,e5,e6,e7,e8)
#undef RVT
      A = C; Bv = D; W -= 8;
    }
  }
  float wet = sigmoidf_(wetl[0]);
  float accs[8] = {acc0,acc1,acc2,acc3,acc4,acc5,acc6,acc7};
  #pragma unroll
  for (int j = 0; j < 8; ++j) {
    long t = (long)tbase + 8 * tid + j;
    if (t < (long)TOT) {
      float av = arow[APAD + t];
      out[(size_t)b * TOT + t] = (1.0f - wet) * av + wet * accs[j];
    }
  }
}

// ---------------- launch ----------------
extern "C" void kernel_launch(void* const* d_in, const int* in_sizes, int n_in,
                              void* d_out, int out_size, void* d_ws, size_t ws_size,
                              hipStream_t stream) {
  const float* f0       = (const float*)d_in[0];
  const float* loud     = (const float*)d_in[1];
  const float* gender   = (const float*)d_in[2];
  const float* age      = (const float*)d_in[3];
  const float* z        = (const float*)d_in[4];
  const float* noise    = (const float*)d_in[5];
  const float* W_in     = (const float*)d_in[6];
  const float* b_in     = (const float*)d_in[7];
  const float* W_ih     = (const float*)d_in[8];
  const float* W_hh     = (const float*)d_in[9];
  const float* b_ih     = (const float*)d_in[10];
  const float* b_hh     = (const float*)d_in[11];
  const float* W_oq     = (const float*)d_in[12];
  const float* b_oq     = (const float*)d_in[13];
  const float* W_vg     = (const float*)d_in[14];
  const float* b_vg     = (const float*)d_in[15];
  const float* W_ug     = (const float*)d_in[16];
  const float* b_ug     = (const float*)d_in[17];
  const float* W_ff     = (const float*)d_in[18];
  const float* b_ff     = (const float*)d_in[19];
  const float* W_fb     = (const float*)d_in[20];
  const float* b_fb     = (const float*)d_in[21];
  const float* rev_ir   = (const float*)d_in[22];
  const float* wet_l    = (const float*)d_in[23];

  float* out = (float*)d_out;
  char* ws = (char*)d_ws;
  float* x      = (float*)(ws + OFF_X);
  float* gi     = (float*)(ws + OFF_GI);
  float* hs     = (float*)(ws + OFF_HS);
  float* filtR  = (float*)(ws + OFF_FILTR);
  float* oqw    = (float*)(ws + OFF_OQ);
  float* vgw    = (float*)(ws + OFF_VG);
  float* ugw    = (float*)(ws + OFF_UG);
  float* ffw    = (float*)(ws + OFF_FFW);
  float* fbw    = (float*)(ws + OFF_FBW);
  float* startw = (float*)(ws + OFF_START);
  float* f0m    = (float*)(ws + OFF_F0M);
  unsigned long long* hbuf = (unsigned long long*)(ws + OFF_HBUF);
  float* exc    = (float*)(ws + OFF_EXC);
  float* irp    = (float*)(ws + OFF_IRP);
  float* audio  = (float*)(ws + OFF_AUDIO);

  // zero tagged h double-buffer (16KB, overlays ffw until k_heads) + audio acc
  hipMemsetAsync(ws + OFF_HBUF, 0, 16384, stream);
  hipMemsetAsync(ws + OFF_AUDIO, 0, (size_t)4 * AROW * 4, stream);

  k_f0mean<<<4, 256, 0, stream>>>(f0, f0m);
  k_inproj<<<512, 256, 0, stream>>>(f0, loud, gender, age, z, f0m, W_in, b_in, x);
  k_gemm_gi<<<dim3(24, 128), 256, 0, stream>>>(x, W_ih, b_ih, gi);
  k_gru<<<128, 256, 0, stream>>>(W_hh, b_hh, gi, hs, hbuf);
  k_heads<<<8192, 256, 0, stream>>>(hs, W_oq, b_oq, W_vg, b_vg, W_ug, b_ug,
                                    W_ff, b_ff, W_fb, b_fb, out, oqw, vgw, ugw, ffw, fbw);
  k_scan<<<4, 256, 0, stream>>>(f0, startw);
  k_excite<<<8192, 256, 0, stream>>>(f0, noise, startw, oqw, vgw, ugw, exc);
  k_ir<<<8192, 256, 0, stream>>>(ffw, fbw, filtR);
  k_conv<<<8192, 256, 0, stream>>>(exc, filtR, audio);
  k_padir<<<94, 256, 0, stream>>>(rev_ir, irp);   // gi region dead after k_gru
  k_reverb<<<dim3(257, 4), 256, 0, stream>>>(audio, irp, wet_l, out);
}

// Round 11
// 4947.768 us; speedup vs baseline: 1.2983x; 1.1445x over previous
//
#include <hip/hip_runtime.h>
#include <hip/hip_bf16.h>
#include <math.h>

// ---------------- constants ----------------
#define PI_F 3.14159265358979323846f
#define TWO_PI_F 6.283185307179586f

constexpr int BB = 4;            // batch
constexpr int FF_ = 2048;        // frames
constexpr int RC = 512;          // rnn channels
constexpr int HOP = 256;
constexpr int KK = 1024;         // FIR len
constexpr int LL = HOP + KK - 1; // 1279
constexpr size_t TOT = 525311;   // (F-1)*HOP + L
constexpr int APAD = 24064;      // zero pad in front of audio rows (>= REV-1, mult of 64)
constexpr size_t AROW = 549376;  // APAD + 525312
constexpr int REV = 24000;

// output offsets (floats)
constexpr size_t O1 = 2101244;   // oq
constexpr size_t O2 = 2109436;   // v_gain
constexpr size_t O3 = 2117628;   // u_gain
constexpr size_t O4 = 2125820;   // ff
constexpr size_t O5 = 2158588;   // fb

// workspace offsets (bytes)
constexpr size_t OFF_X      = 0;                 // 8192*512*4
constexpr size_t OFF_GI     = 16777216;          // 8192*1536*4
constexpr size_t OFF_HS     = 67108864;          // 8192*512*4
constexpr size_t OFF_OQ     = 83886080;
constexpr size_t OFF_VG     = 83918848;
constexpr size_t OFF_UG     = 83951616;
constexpr size_t OFF_FFW    = 83984384;          // also hbuf (16KB) during k_gru; ffw written after
constexpr size_t OFF_FBW    = 84115456;
constexpr size_t OFF_START  = 84246528;
constexpr size_t OFF_F0M    = 84279296;
constexpr size_t OFF_IRPK   = 50331648;          // packed f16-pair reverb taps (12032 dwords) — gi dead-zone
constexpr size_t OFF_AUDIO  = 92684800;          // 4*549376*4

constexpr size_t OFF_HBUF   = OFF_FFW;           // 2 slots x 4 batch x 256 words x 8B = 16KB

__device__ __forceinline__ float softplusf(float x) {
  return x > 20.0f ? x : log1pf(expf(x));
}
__device__ __forceinline__ float sigmoidf_(float x) {
  return 1.0f / (1.0f + expf(-x));
}

typedef _Float16 half2v __attribute__((ext_vector_type(2)));
typedef _Float16 f16x8 __attribute__((ext_vector_type(8)));
typedef float f32x4 __attribute__((ext_vector_type(4)));

__device__ __forceinline__ float dot2f(unsigned wa, unsigned hb, float acc) {
#if __has_builtin(__builtin_amdgcn_fdot2)
  union { unsigned u; half2v h; } A, B;
  A.u = wa; B.u = hb;
  return __builtin_amdgcn_fdot2(A.h, B.h, acc, false);
#else
  union { unsigned u; _Float16 h[2]; } A, B;
  A.u = wa; B.u = hb;
  return fmaf((float)A.h[0], (float)B.h[0], fmaf((float)A.h[1], (float)B.h[1], acc));
#endif
}

// ---------------- f0 mean per batch ----------------
__global__ __launch_bounds__(256) void k_f0mean(const float* __restrict__ f0, float* __restrict__ f0m) {
  int b = blockIdx.x, tid = threadIdx.x;
  float s = 0.f;
  for (int t = tid; t < FF_; t += 256) s += f0[b*FF_ + t];
  #pragma unroll
  for (int m = 1; m < 64; m <<= 1) s += __shfl_xor(s, m);
  __shared__ float ws4[4];
  if ((tid & 63) == 0) ws4[tid >> 6] = s;
  __syncthreads();
  if (tid == 0) f0m[b] = (ws4[0] + ws4[1] + ws4[2] + ws4[3]) * (1.0f / 2048.0f);
}

// ---------------- input projection: x = relu(concat @ W_in^T + b_in) ----------------
__global__ __launch_bounds__(256) void k_inproj(
    const float* __restrict__ f0, const float* __restrict__ loud,
    const float* __restrict__ gender, const float* __restrict__ age,
    const float* __restrict__ z, const float* __restrict__ f0m,
    const float* __restrict__ Win, const float* __restrict__ bin,
    float* __restrict__ x)
{
  __shared__ float inp[16 * 28];
  int r0 = blockIdx.x * 16;   // bf base
  int tid = threadIdx.x;
  for (int i = tid; i < 16 * 28; i += 256) {
    int r = i / 28, c = i % 28;
    int bf = r0 + r, b = bf >> 11;
    float v;
    if (c == 0)       v = f0[bf] - f0m[b];
    else if (c == 1)  v = loud[bf];
    else if (c < 4)   v = gender[(size_t)bf*2 + (c - 2)];
    else if (c < 12)  v = age[(size_t)bf*8 + (c - 4)];
    else              v = z[(size_t)bf*16 + (c - 12)];
    inp[i] = v;
  }
  __syncthreads();
  for (int o = tid; o < 16 * 512; o += 256) {
    int r = o >> 9, j = o & 511;
    const float* w = Win + j * 28;
    const float* ip = inp + r * 28;
    float a = bin[j];
    #pragma unroll
    for (int c2 = 0; c2 < 28; ++c2) a = fmaf(w[c2], ip[c2], a);
    x[(size_t)(r0 + r) * 512 + j] = fmaxf(a, 0.0f);
  }
}

// ---------------- GEMM v2 (MFMA f16): gi = x @ W_ih^T + b_ih ----------------
__global__ __launch_bounds__(256) void k_gemm_gi(
    const float* __restrict__ A, const float* __restrict__ Bw,
    const float* __restrict__ bias, float* __restrict__ C)
{
  __shared__ unsigned As[64 * 20];  // f16-pair dwords, row stride 20
  __shared__ unsigned Bs[64 * 20];
  int tid = threadIdx.x;
  int n0 = blockIdx.x * 64, m0 = blockIdx.y * 64;
  const int w = tid >> 6;           // wave 0..3
  const int lane = tid & 63;
  const int mrow0 = (w >> 1) * 32;
  const int ncol0 = (w & 1) * 32;
  const int lm = lane & 15;
  const int quad = lane >> 4;

  f32x4 acc00 = {0.f,0.f,0.f,0.f}, acc01 = {0.f,0.f,0.f,0.f};
  f32x4 acc10 = {0.f,0.f,0.f,0.f}, acc11 = {0.f,0.f,0.f,0.f};

  for (int k0 = 0; k0 < 512; k0 += 32) {
    __syncthreads();
    for (int i = tid; i < 1024; i += 256) {
      int r = i >> 4, d = i & 15;
      float2 av = *(const float2*)(A + (size_t)(m0 + r) * 512 + k0 + 2 * d);
      float2 bv = *(const float2*)(Bw + (size_t)(n0 + r) * 512 + k0 + 2 * d);
      union { unsigned u32; _Float16 h[2]; } pa, pb;
      pa.h[0] = (_Float16)av.x; pa.h[1] = (_Float16)av.y;
      pb.h[0] = (_Float16)bv.x; pb.h[1] = (_Float16)bv.y;
      As[r * 20 + d] = pa.u32;
      Bs[r * 20 + d] = pb.u32;
    }
    __syncthreads();
    union { uint4 u; f16x8 h; } a0, a1, b0, b1;
    a0.u = *(const uint4*)&As[(mrow0 + lm) * 20 + quad * 4];
    a1.u = *(const uint4*)&As[(mrow0 + 16 + lm) * 20 + quad * 4];
    b0.u = *(const uint4*)&Bs[(ncol0 + lm) * 20 + quad * 4];
    b1.u = *(const uint4*)&Bs[(ncol0 + 16 + lm) * 20 + quad * 4];
    acc00 = __builtin_amdgcn_mfma_f32_16x16x32_f16(a0.h, b0.h, acc00, 0, 0, 0);
    acc01 = __builtin_amdgcn_mfma_f32_16x16x32_f16(a0.h, b1.h, acc01, 0, 0, 0);
    acc10 = __builtin_amdgcn_mfma_f32_16x16x32_f16(a1.h, b0.h, acc10, 0, 0, 0);
    acc11 = __builtin_amdgcn_mfma_f32_16x16x32_f16(a1.h, b1.h, acc11, 0, 0, 0);
  }
  #pragma unroll
  for (int sm = 0; sm < 2; ++sm) {
    #pragma unroll
    for (int sn = 0; sn < 2; ++sn) {
      const f32x4& ac = sm ? (sn ? acc11 : acc10) : (sn ? acc01 : acc00);
      int col = n0 + ncol0 + sn * 16 + lm;
      float bb = bias[col];
      #pragma unroll
      for (int rg = 0; rg < 4; ++rg) {
        int row = m0 + mrow0 + sm * 16 + quad * 4 + rg;
        C[(size_t)row * 1536 + col] = ac[rg] + bb;
      }
    }
  }
}

// ---------------- persistent GRU v7: 2-row h reuse, 128 WGs (3.17 ms winner) ----------------
__global__ __launch_bounds__(256, 1) void k_gru(
    const float* __restrict__ Whh, const float* __restrict__ bhh,
    const float* __restrict__ gi, float* __restrict__ hs,
    unsigned long long* hbuf)
{
  __shared__ unsigned hs2[2][292];   // 8 pieces x 36-dword stride per parity
  __shared__ float red[2][384];      // [row*8 + piece]
  __shared__ float bhh_s[48];

  const int tid = threadIdx.x;
  const int b   = blockIdx.x & 3;    // batch / group
  const int wgi = blockIdx.x >> 2;   // 0..31
  const int u0  = wgi * 16;
  const int piece = tid & 7;         // dot threads (tid<192)
  const int rp    = tid >> 3;        // row pair 0..23

  unsigned w0r[32], w1r[32];
  if (tid < 192) {
    int r0 = 2 * rp, r1 = 2 * rp + 1;
    const float* s0 = Whh + (size_t)((r0 >> 4) * 512 + u0 + (r0 & 15)) * 512 + piece * 64;
    const float* s1 = Whh + (size_t)((r1 >> 4) * 512 + u0 + (r1 & 15)) * 512 + piece * 64;
    #pragma unroll
    for (int j = 0; j < 32; ++j) {
      float2 a = *(const float2*)(s0 + 2 * j);
      float2 c = *(const float2*)(s1 + 2 * j);
      union { unsigned u32; _Float16 hh[2]; } ca, cb;
      ca.hh[0] = (_Float16)a.x; ca.hh[1] = (_Float16)a.y;
      cb.hh[0] = (_Float16)c.x; cb.hh[1] = (_Float16)c.y;
      w0r[j] = ca.u32; w1r[j] = cb.u32;
    }
  } else {
    #pragma unroll
    for (int j = 0; j < 32; ++j) { w0r[j] = 0u; w1r[j] = 0u; }
  }
  if (tid < 48) bhh_s[tid] = bhh[(tid >> 4) * 512 + u0 + (tid & 15)];
  __syncthreads();

  float hprev = 0.0f;

  #pragma unroll 1
  for (unsigned t = 0; t < 2048; ++t) {
    const int p = (int)(t & 1u);
    float gir = 0.f, giz = 0.f, gin = 0.f;
    if (tid < 16) {
      const float* gp = gi + (size_t)(b * 2048 + (int)t) * 1536 + u0 + tid;
      gir = gp[0]; giz = gp[512]; gin = gp[1024];
    }
    {
      const unsigned long long* pp = hbuf + ((size_t)p * 4 + b) * 256 + tid;
      unsigned long long w = __hip_atomic_load(pp, __ATOMIC_RELAXED, __HIP_MEMORY_SCOPE_AGENT);
      while ((unsigned)(w >> 32) != t)
        w = __hip_atomic_load(pp, __ATOMIC_RELAXED, __HIP_MEMORY_SCOPE_AGENT);
      hs2[p][(tid >> 5) * 36 + (tid & 31)] = (unsigned)w;
    }
    __syncthreads();
    if (tid < 192) {
      const unsigned* hp = &hs2[p][piece * 36];
      float a00 = 0.f, a01 = 0.f, a10 = 0.f, a11 = 0.f;
      #pragma unroll
      for (int i = 0; i < 8; ++i) {
        uint4 h4 = *(const uint4*)(hp + 4 * i);
        a00 = dot2f(w0r[4 * i + 0], h4.x, a00);
        a01 = dot2f(w0r[4 * i + 1], h4.y, a01);
        a00 = dot2f(w0r[4 * i + 2], h4.z, a00);
        a01 = dot2f(w0r[4 * i + 3], h4.w, a01);
        a10 = dot2f(w1r[4 * i + 0], h4.x, a10);
        a11 = dot2f(w1r[4 * i + 1], h4.y, a11);
        a10 = dot2f(w1r[4 * i + 2], h4.z, a10);
        a11 = dot2f(w1r[4 * i + 3], h4.w, a11);
      }
      red[p][(2 * rp) * 8 + piece]     = a00 + a01;
      red[p][(2 * rp + 1) * 8 + piece] = a10 + a11;
    }
    __syncthreads();
    if (tid < 16) {
      const float* r0p = &red[p][tid * 8];
      const float* r1p = &red[p][(16 + tid) * 8];
      const float* r2p = &red[p][(32 + tid) * 8];
      float4 q0 = *(const float4*)r0p, q1 = *(const float4*)(r0p + 4);
      float4 z0 = *(const float4*)r1p, z1 = *(const float4*)(r1p + 4);
      float4 n0 = *(const float4*)r2p, n1 = *(const float4*)(r2p + 4);
      float ghr = ((q0.x + q0.y) + (q0.z + q0.w)) + ((q1.x + q1.y) + (q1.z + q1.w)) + bhh_s[tid];
      float ghz = ((z0.x + z0.y) + (z0.z + z0.w)) + ((z1.x + z1.y) + (z1.z + z1.w)) + bhh_s[16 + tid];
      float ghn = ((n0.x + n0.y) + (n0.z + n0.w)) + ((n1.x + n1.y) + (n1.z + n1.w)) + bhh_s[32 + tid];
      float r  = sigmoidf_(gir + ghr);
      float zg = sigmoidf_(giz + ghz);
      float n  = tanhf(gin + r * ghn);
      float hnew = (1.0f - zg) * n + zg * hprev;
      hprev = hnew;
      hs[(size_t)(b * 2048 + (int)t) * 512 + u0 + tid] = hnew;
      float hpart = __shfl_xor(hnew, 1);
      if ((tid & 1) == 0) {
        union { unsigned u32; _Float16 hh[2]; } pk;
        pk.hh[0] = (_Float16)hnew;
        pk.hh[1] = (_Float16)hpart;
        unsigned long long wq = ((unsigned long long)(t + 1u) << 32) | (unsigned long long)pk.u32;
        __hip_atomic_store(hbuf + ((size_t)((t + 1u) & 1u) * 4 + b) * 256 + (u0 >> 1) + (tid >> 1),
                           wq, __ATOMIC_RELAXED, __HIP_MEMORY_SCOPE_AGENT);
      }
    }
  }
}

// ---------------- heads: oq, v_gain, u_gain, ff(cumsum), fb ----------------
__global__ __launch_bounds__(256) void k_heads(
    const float* __restrict__ hs,
    const float* __restrict__ Woq, const float* __restrict__ boq,
    const float* __restrict__ Wvg, const float* __restrict__ bvg,
    const float* __restrict__ Wug, const float* __restrict__ bug,
    const float* __restrict__ Wff, const float* __restrict__ bff,
    const float* __restrict__ Wfb, const float* __restrict__ bfb,
    float* __restrict__ out,
    float* __restrict__ oqw, float* __restrict__ vgw, float* __restrict__ ugw,
    float* __restrict__ ffw, float* __restrict__ fbw)
{
  int bf = blockIdx.x, tid = threadIdx.x;
  const float* h = hs + (size_t)bf * 512;
  float p[11];
  #pragma unroll
  for (int i = 0; i < 11; ++i) p[i] = 0.f;
  for (int k = tid; k < 512; k += 256) {
    float hv = h[k];
    p[0] = fmaf(Woq[k], hv, p[0]);
    p[1] = fmaf(Wvg[k], hv, p[1]);
    p[2] = fmaf(Wug[k], hv, p[2]);
    p[3] = fmaf(Wff[k], hv, p[3]);
    p[4] = fmaf(Wff[512 + k], hv, p[4]);
    p[5] = fmaf(Wff[1024 + k], hv, p[5]);
    p[6] = fmaf(Wff[1536 + k], hv, p[6]);
    p[7] = fmaf(Wfb[k], hv, p[7]);
    p[8] = fmaf(Wfb[512 + k], hv, p[8]);
    p[9] = fmaf(Wfb[1024 + k], hv, p[9]);
    p[10] = fmaf(Wfb[1536 + k], hv, p[10]);
  }
  #pragma unroll
  for (int i = 0; i < 11; ++i) {
    float v = p[i];
    #pragma unroll
    for (int m = 1; m < 64; m <<= 1) v += __shfl_xor(v, m);
    p[i] = v;
  }
  __shared__ float r4[4][11];
  if ((tid & 63) == 0) {
    int w = tid >> 6;
    #pragma unroll
    for (int i = 0; i < 11; ++i) r4[w][i] = p[i];
  }
  __syncthreads();
  if (tid == 0) {
    float s[11];
    #pragma unroll
    for (int i = 0; i < 11; ++i) s[i] = r4[0][i] + r4[1][i] + r4[2][i] + r4[3][i];
    float oqv = sigmoidf_(s[0] + boq[0]);
    float vg = softplusf(s[1] + bvg[0]);
    float ug = softplusf(s[2] + bug[0]);
    out[O1 + bf] = oqv; oqw[bf] = oqv;
    out[O2 + bf] = vg;  vgw[bf] = vg;
    out[O3 + bf] = ug;  ugw[bf] = ug;
    float run = 200.0f;
    #pragma unroll
    for (int j = 0; j < 4; ++j) {
      run += softplusf(s[3 + j] + bff[j]);
      out[O4 + (size_t)bf * 4 + j] = run; ffw[(size_t)bf * 4 + j] = run;
    }
    #pragma unroll
    for (int j = 0; j < 4; ++j) {
      float g = softplusf(s[7 + j] + bfb[j]) + 50.0f;
      out[O5 + (size_t)bf * 4 + j] = g; fbw[(size_t)bf * 4 + j] = g;
    }
  }
}

// ---------------- per-batch prefix scan of cycles -> start phase ----------------
__global__ __launch_bounds__(256) void k_scan(const float* __restrict__ f0, float* __restrict__ startw) {
  __shared__ float ts[256];
  int b = blockIdx.x, tid = threadIdx.x;
  const float CY = 256.0f / 24000.0f;
  float c[8], run = 0.f;
  int base = b * 2048 + tid * 8;
  #pragma unroll
  for (int j = 0; j < 8; ++j) { c[j] = run; run += f0[base + j] * CY; }
  ts[tid] = run;
  __syncthreads();
  for (int off = 1; off < 256; off <<= 1) {
    float v = (tid >= off) ? ts[tid - off] : 0.0f;
    __syncthreads();
    ts[tid] += v;
    __syncthreads();
  }
  float excl = (tid == 0) ? 0.0f : ts[tid - 1];
  #pragma unroll
  for (int j = 0; j < 8; ++j) {
    float st = excl + c[j];
    startw[base + j] = st - floorf(st);
  }
}

// ---------------- fused synth: excitation + formant IR + conv/OLA ----------------
// exc and filt live only in LDS (saves exc/filtR global round trips + 2 launches).
__global__ __launch_bounds__(256) void k_synth(
    const float* __restrict__ f0, const float* __restrict__ noise,
    const float* __restrict__ startw, const float* __restrict__ oqw,
    const float* __restrict__ vgw, const float* __restrict__ ugw,
    const float* __restrict__ ffw, const float* __restrict__ fbw,
    float* __restrict__ audio)
{
  __shared__ float es[256];
  __shared__ float fp[1536];
  __shared__ float ffs[4], fbs[4], ssc[1], wmax[4];
  int bf = blockIdx.x, tid = threadIdx.x;
  int b = bf >> 11, f = bf & 2047;

  // excitation -> es
  {
    float st = startw[bf], f0v = f0[bf], oqv = oqw[bf], vg = vgw[bf], ug = ugw[bf];
    float total = st + f0v * ((float)tid * (1.0f / 24000.0f));
    float phi = total - floorf(total);
    float peak = oqv * 0.66f;
    float rise = 0.5f * (1.0f - cosf(PI_F * phi / (peak + 1e-6f)));
    float fall = cosf(PI_F * (phi - peak) / (2.0f * (oqv - peak) + 1e-6f));
    float v = (phi < peak) ? rise : ((phi < oqv) ? fall : 0.0f);
    es[tid] = v * vg + noise[(size_t)bf * 256 + tid] * ug;
  }
  if (tid < 4) { ffs[tid] = ffw[(size_t)bf * 4 + tid]; fbs[tid] = fbw[(size_t)bf * 4 + tid]; }
  fp[tid] = 0.0f;          // fp[0..255]
  fp[1280 + tid] = 0.0f;   // fp[1280..1535]
  __syncthreads();

  // formant IR + normalization -> fp[256..1279] reversed
  float vals[4];
  float am = 0.f;
  #pragma unroll
  for (int it = 0; it < 4; ++it) {
    int k = it * 256 + tid;
    float t = (float)k * (1.0f / 24000.0f);
    float s = 0.f;
    #pragma unroll
    for (int j = 0; j < 4; ++j)
      s += expf(-PI_F * fbs[j] * t) * sinf(TWO_PI_F * ffs[j] * t);
    vals[it] = s;
    am = fmaxf(am, fabsf(s));
  }
  #pragma unroll
  for (int m = 1; m < 64; m <<= 1) am = fmaxf(am, __shfl_xor(am, m));
  if ((tid & 63) == 0) wmax[tid >> 6] = am;
  __syncthreads();
  if (tid == 0) ssc[0] = fmaxf(fmaxf(wmax[0], wmax[1]), fmaxf(wmax[2], wmax[3])) + 1e-8f;
  __syncthreads();
  float inv = 1.0f / ssc[0];
  #pragma unroll
  for (int it = 0; it < 4; ++it) {
    int k = it * 256 + tid;
    fp[256 + (1023 - k)] = vals[it] * inv;
  }
  __syncthreads();

  // conv (full) + overlap-add
  int n0 = tid * 5;
  float V0 = fp[n0 + 256], V1 = fp[n0 + 257], V2 = fp[n0 + 258], V3 = fp[n0 + 259], V4 = fp[n0 + 260];
  float a0 = 0.f, a1 = 0.f, a2 = 0.f, a3 = 0.f, a4 = 0.f;
  #pragma unroll 4
  for (int m = 0; m < 256; ++m) {
    float e = es[m];
    a0 = fmaf(e, V0, a0); a1 = fmaf(e, V1, a1); a2 = fmaf(e, V2, a2);
    a3 = fmaf(e, V3, a3); a4 = fmaf(e, V4, a4);
    V4 = V3; V3 = V2; V2 = V1; V1 = V0;
    V0 = fp[n0 + 255 - m];
  }
  float* arow = audio + (size_t)b * AROW + APAD + (size_t)f * 256;
  if (n0 + 0 < LL) atomicAdd(&arow[n0 + 0], a0);
  if (n0 + 1 < LL) atomicAdd(&arow[n0 + 1], a1);
  if (n0 + 2 < LL) atomicAdd(&arow[n0 + 2], a2);
  if (n0 + 3 < LL) atomicAdd(&arow[n0 + 3], a3);
  if (n0 + 4 < LL) atomicAdd(&arow[n0 + 4], a4);
}

// ---------------- pack reverb ir as f16 pairs, zero-padded to 24064 ----------------
__global__ __launch_bounds__(256) void k_padir(const float* __restrict__ ir, unsigned* __restrict__ irpk) {
  int d = blockIdx.x * 256 + threadIdx.x;
  if (d < 12032) {
    float a = (2 * d < REV) ? ir[2 * d] : 0.0f;
    float b = (2 * d + 1 < REV) ? ir[2 * d + 1] : 0.0f;
    union { unsigned u32; _Float16 h[2]; } pk;
    pk.h[0] = (_Float16)a; pk.h[1] = (_Float16)b;
    irpk[d] = pk.u32;
  }
}

// ---------------- reverb FIR v5: f16x2 dot2, reversed packed windows ----------------
// audio window staged as reversed f16-pair copies (even + odd shift) so every
// output parity reads aligned pairs; taps pre-packed f16 pairs (wave-uniform
// uint4 -> scalar loads). fp32 accumulators; dry path fp32.
__global__ __launch_bounds__(256) void k_reverb(
    const float* __restrict__ audio, const unsigned* __restrict__ irpk,
    const float* __restrict__ wetl, float* __restrict__ out)
{
  __shared__ float win[2305];     // forward fp32 window: win[i] = arow[B0-1+i]
  __shared__ unsigned pkE[1152];  // {a(B0+2303-2d), a(B0+2302-2d)}
  __shared__ unsigned pkO[1152];  // {a(B0+2302-2d), a(B0+2301-2d)}
  int tb = blockIdx.x, b = blockIdx.y, tid = threadIdx.x;
  int tbase = tb * 2048;
  const float* arow = audio + (size_t)b * AROW;
  const uint4* irq = (const uint4*)irpk;
  float acc0=0.f,acc1=0.f,acc2=0.f,acc3=0.f,acc4=0.f,acc5=0.f,acc6=0.f,acc7=0.f;

  for (int c = 0; c < 94; ++c) {
    __syncthreads();
    int B0w = APAD + tbase - c * 256 - 257;   // window base minus 1 (can be -1)
    for (int i = tid; i < 2305; i += 256) {
      int g = B0w + i;
      win[i] = (g >= 0 && g < (int)AROW) ? arow[g] : 0.0f;
    }
    __syncthreads();
    for (int d = tid; d < 1152; d += 256) {
      float w2 = win[2304 - 2 * d];
      float w1 = win[2303 - 2 * d];
      float w0 = win[2302 - 2 * d];
      union { unsigned u32; _Float16 h[2]; } pe, po;
      pe.h[0] = (_Float16)w2; pe.h[1] = (_Float16)w1;
      po.h[0] = (_Float16)w1; po.h[1] = (_Float16)w0;
      pkE[d] = pe.u32;
      pkO[d] = po.u32;
    }
    __syncthreads();
    #pragma unroll 1
    for (int m = 0; m < 32; ++m) {
      int e0 = 1020 - 4 * tid + 4 * m;
      uint4 E0 = *(const uint4*)&pkE[e0];
      uint4 E1 = *(const uint4*)&pkE[e0 + 4];
      uint4 O0 = *(const uint4*)&pkO[e0];
      uint4 O1 = *(const uint4*)&pkO[e0 + 4];
      uint4 tp = irq[c * 32 + m];
      // s=0 (tap pair tp.x)
      acc7 = dot2f(tp.x, E0.x, acc7); acc5 = dot2f(tp.x, E0.y, acc5);
      acc3 = dot2f(tp.x, E0.z, acc3); acc1 = dot2f(tp.x, E0.w, acc1);
      acc6 = dot2f(tp.x, O0.x, acc6); acc4 = dot2f(tp.x, O0.y, acc4);
      acc2 = dot2f(tp.x, O0.z, acc2); acc0 = dot2f(tp.x, O0.w, acc0);
      // s=1
      acc7 = dot2f(tp.y, E0.y, acc7); acc5 = dot2f(tp.y, E0.z, acc5);
      acc3 = dot2f(tp.y, E0.w, acc3); acc1 = dot2f(tp.y, E1.x, acc1);
      acc6 = dot2f(tp.y, O0.y, acc6); acc4 = dot2f(tp.y, O0.z, acc4);
      acc2 = dot2f(tp.y, O0.w, acc2); acc0 = dot2f(tp.y, O1.x, acc0);
      // s=2
      acc7 = dot2f(tp.z, E0.z, acc7); acc5 = dot2f(tp.z, E0.w, acc5);
      acc3 = dot2f(tp.z, E1.x, acc3); acc1 = dot2f(tp.z, E1.y, acc1);
      acc6 = dot2f(tp.z, O0.z, acc6); acc4 = dot2f(tp.z, O0.w, acc4);
      acc2 = dot2f(tp.z, O1.x, acc2); acc0 = dot2f(tp.z, O1.y, acc0);
      // s=3
      acc7 = dot2f(tp.w, E0.w, acc7); acc5 = dot2f(tp.w, E1.x, acc5);
      acc3 = dot2f(tp.w, E1.y, acc3); acc1 = dot2f(tp.w, E1.z, acc1);
      acc6 = dot2f(tp.w, O0.w, acc6); acc4 = dot2f(tp.w, O1.x, acc4);
      acc2 = dot2f(tp.w, O1.y, acc2); acc0 = dot2f(tp.w, O1.z, acc0);
    }
  }
  float wet = sigmoidf_(wetl[0]);
  float accs[8] = {acc0,acc1,acc2,acc3,acc4,acc5,acc6,acc7};
  #pragma unroll
  for (int j = 0; j < 8; ++j) {
    long t = (long)tbase + 8 * tid + j;
    if (t < (long)TOT) {
      float av = arow[APAD + t];
      out[(size_t)b * TOT + t] = (1.0f - wet) * av + wet * accs[j];
    }
  }
}

// ---------------- launch ----------------
extern "C" void kernel_launch(void* const* d_in, const int* in_sizes, int n_in,
                              void* d_out, int out_size, void* d_ws, size_t ws_size,
                              hipStream_t stream) {
  const float* f0       = (const float*)d_in[0];
  const float* loud     = (const float*)d_in[1];
  const float* gender   = (const float*)d_in[2];
  const float* age      = (const float*)d_in[3];
  const float* z        = (const float*)d_in[4];
  const float* noise    = (const float*)d_in[5];
  const float* W_in     = (const float*)d_in[6];
  const float* b_in     = (const float*)d_in[7];
  const float* W_ih     = (const float*)d_in[8];
  const float* W_hh     = (const float*)d_in[9];
  const float* b_ih     = (const float*)d_in[10];
  const float* b_hh     = (const float*)d_in[11];
  const float* W_oq     = (const float*)d_in[12];
  const float* b_oq     = (const float*)d_in[13];
  const float* W_vg     = (const float*)d_in[14];
  const float* b_vg     = (const float*)d_in[15];
  const float* W_ug     = (const float*)d_in[16];
  const float* b_ug     = (const float*)d_in[17];
  const float* W_ff     = (const float*)d_in[18];
  const float* b_ff     = (const float*)d_in[19];
  const float* W_fb     = (const float*)d_in[20];
  const float* b_fb     = (const float*)d_in[21];
  const float* rev_ir   = (const float*)d_in[22];
  const float* wet_l    = (const float*)d_in[23];

  float* out = (float*)d_out;
  char* ws = (char*)d_ws;
  float* x      = (float*)(ws + OFF_X);
  float* gi     = (float*)(ws + OFF_GI);
  float* hs     = (float*)(ws + OFF_HS);
  float* oqw    = (float*)(ws + OFF_OQ);
  float* vgw    = (float*)(ws + OFF_VG);
  float* ugw    = (float*)(ws + OFF_UG);
  float* ffw    = (float*)(ws + OFF_FFW);
  float* fbw    = (float*)(ws + OFF_FBW);
  float* startw = (float*)(ws + OFF_START);
  float* f0m    = (float*)(ws + OFF_F0M);
  unsigned long long* hbuf = (unsigned long long*)(ws + OFF_HBUF);
  unsigned* irpk = (unsigned*)(ws + OFF_IRPK);
  float* audio  = (float*)(ws + OFF_AUDIO);

  // zero tagged h double-buffer (16KB, overlays ffw until k_heads) + audio acc
  hipMemsetAsync(ws + OFF_HBUF, 0, 16384, stream);
  hipMemsetAsync(ws + OFF_AUDIO, 0, (size_t)4 * AROW * 4, stream);

  k_f0mean<<<4, 256, 0, stream>>>(f0, f0m);
  k_inproj<<<512, 256, 0, stream>>>(f0, loud, gender, age, z, f0m, W_in, b_in, x);
  k_gemm_gi<<<dim3(24, 128), 256, 0, stream>>>(x, W_ih, b_ih, gi);
  k_gru<<<128, 256, 0, stream>>>(W_hh, b_hh, gi, hs, hbuf);
  k_heads<<<8192, 256, 0, stream>>>(hs, W_oq, b_oq, W_vg, b_vg, W_ug, b_ug,
                                    W_ff, b_ff, W_fb, b_fb, out, oqw, vgw, ugw, ffw, fbw);
  k_scan<<<4, 256, 0, stream>>>(f0, startw);
  k_synth<<<8192, 256, 0, stream>>>(f0, noise, startw, oqw, vgw, ugw, ffw, fbw, audio);
  k_padir<<<47, 256, 0, stream>>>(rev_ir, irpk);   // gi region dead after k_gru
  k_reverb<<<dim3(257, 4), 256, 0, stream>>>(audio, irpk, wet_l, out);
}